// Round 2
// baseline (3507.162 us; speedup 1.0000x reference)
//
#include <hip/hip_runtime.h>
#include <hip/hip_bf16.h>

namespace {

constexpr int T_SEQ = 512;
constexpr int B_SZ  = 1024;
constexpr int H_DIM = 128;
constexpr int RPB   = 4;       // batch rows per block
constexpr int NTHR  = 512;     // 8 waves; = RPB * H_DIM combine tasks

__device__ __forceinline__ float fast_sigmoid(float x) {
  x = fminf(fmaxf(x, -30.f), 30.f);
  const float e = __expf(-x);
  return 1.f / (1.f + e);
}
__device__ __forceinline__ float fast_tanh(float x) {
  x = fminf(fmaxf(x, -15.f), 15.f);
  const float e = __expf(2.f * x);
  return 1.f - 2.f / (e + 1.f);
}

__device__ __forceinline__ float ld_in(const float* p) { return *p; }
__device__ __forceinline__ float ld_in(const __hip_bfloat16* p) { return __bfloat162float(*p); }
__device__ __forceinline__ void st_out(float* p, float v) { *p = v; }
__device__ __forceinline__ void st_out(__hip_bfloat16* p, float v) { *p = __float2bfloat16(v); }

// One GRU layer. Block owns RPB batch rows for the whole sequence.
// Thread (j, kq): j = tid&127, kq = tid>>7. Owns gate rows {j, j+H, j+2H}
// x K-quarter kq of BOTH w_ih and w_hh, held in true VGPRs (512-thread
// block -> 256-VGPR budget at 2 waves/SIMD). Each broadcast float4 read of
// x/h feeds 12 FMAs (3 gate rows x 4 lanes of K).
template <int INDIM, typename InT, typename OutT, bool STORE_ALL>
__global__ __launch_bounds__(NTHR, 2)
void gru_layer_kernel(const InT*  __restrict__ in,     // (B, T, INDIM)
                      const float* __restrict__ w_ih,  // (3H, INDIM)
                      const float* __restrict__ w_hh,  // (3H, H)
                      const float* __restrict__ b_ih,  // (3H)
                      const float* __restrict__ b_hh,  // (3H)
                      OutT* __restrict__ out)          // STORE_ALL ? (B,T,H) : (B,H)
{
  constexpr int KQI = INDIM / 4;   // per-thread w_ih K-slice
  constexpr int KQH = H_DIM / 4;   // per-thread w_hh K-slice = 32

  const int tid = threadIdx.x;
  const int j   = tid & (H_DIM - 1);
  const int kq  = tid >> 7;        // 0..3
  const int r0  = blockIdx.x * RPB;

  __shared__ __align__(16) float  h_s[RPB][H_DIM];
  __shared__ __align__(16) float  in_s[RPB][INDIM];
  __shared__ __align__(16) float4 part[RPB][4][H_DIM];  // (r, kq, j) -> (ar, az, xn, hn)

  h_s[tid >> 7][tid & (H_DIM - 1)] = 0.f;   // 512 elems, one per thread

  // ---- weights -> registers (once). 3 gate rows x K-quarter, both mats ----
  float wi[3][KQI];
  float wh[3][KQH];
  #pragma unroll
  for (int g = 0; g < 3; ++g) {
    const float4* si = reinterpret_cast<const float4*>(
        w_ih + (size_t)(g * H_DIM + j) * INDIM + kq * KQI);
    #pragma unroll
    for (int k4 = 0; k4 < KQI / 4; ++k4) {
      const float4 v = si[k4];
      wi[g][4*k4+0] = v.x; wi[g][4*k4+1] = v.y; wi[g][4*k4+2] = v.z; wi[g][4*k4+3] = v.w;
    }
    const float4* sh = reinterpret_cast<const float4*>(
        w_hh + (size_t)(g * H_DIM + j) * H_DIM + kq * KQH);
    #pragma unroll
    for (int k4 = 0; k4 < KQH / 4; ++k4) {
      const float4 v = sh[k4];
      wh[g][4*k4+0] = v.x; wh[g][4*k4+1] = v.y; wh[g][4*k4+2] = v.z; wh[g][4*k4+3] = v.w;
    }
  }
  // combine-phase constants (this thread's combine task is row tid>>7, col j)
  const float bir = b_ih[j],           bhr = b_hh[j];
  const float biz = b_ih[H_DIM + j],   bhz = b_hh[H_DIM + j];
  const float bin_ = b_ih[2*H_DIM + j], bhn = b_hh[2*H_DIM + j];

  // ---- stage t=0 input ----
  const int sr = tid / INDIM;      // INDIM is pow2
  const int sc = tid & (INDIM - 1);
  const bool do_stage = (tid < RPB * INDIM);
  float stg = 0.f;
  if (do_stage) stg = ld_in(in + (size_t)(r0 + sr) * T_SEQ * INDIM + sc);

  __syncthreads();   // h_s init visible

  #pragma unroll 1
  for (int t = 0; t < T_SEQ; ++t) {
    if (do_stage) in_s[sr][sc] = stg;
    __syncthreads();                       // [B1] in_s + h_s ready

    if (do_stage && (t + 1 < T_SEQ))
      stg = ld_in(in + (size_t)(r0 + sr) * T_SEQ * INDIM + (size_t)(t + 1) * INDIM + sc);

    // partial dot products for all RPB rows
    #pragma unroll
    for (int r = 0; r < RPB; ++r) {
      float a0 = 0.f, a1 = 0.f, a2 = 0.f, a3 = 0.f;  // r, z, xn, hn
      const float4* xq = reinterpret_cast<const float4*>(&in_s[r][kq * KQI]);
      #pragma unroll
      for (int k4 = 0; k4 < KQI / 4; ++k4) {
        const float4 v = xq[k4];
        a0 += wi[0][4*k4+0]*v.x; a0 += wi[0][4*k4+1]*v.y; a0 += wi[0][4*k4+2]*v.z; a0 += wi[0][4*k4+3]*v.w;
        a1 += wi[1][4*k4+0]*v.x; a1 += wi[1][4*k4+1]*v.y; a1 += wi[1][4*k4+2]*v.z; a1 += wi[1][4*k4+3]*v.w;
        a2 += wi[2][4*k4+0]*v.x; a2 += wi[2][4*k4+1]*v.y; a2 += wi[2][4*k4+2]*v.z; a2 += wi[2][4*k4+3]*v.w;
      }
      const float4* hq = reinterpret_cast<const float4*>(&h_s[r][kq * KQH]);
      #pragma unroll
      for (int k4 = 0; k4 < KQH / 4; ++k4) {
        const float4 v = hq[k4];
        a0 += wh[0][4*k4+0]*v.x; a0 += wh[0][4*k4+1]*v.y; a0 += wh[0][4*k4+2]*v.z; a0 += wh[0][4*k4+3]*v.w;
        a1 += wh[1][4*k4+0]*v.x; a1 += wh[1][4*k4+1]*v.y; a1 += wh[1][4*k4+2]*v.z; a1 += wh[1][4*k4+3]*v.w;
        a3 += wh[2][4*k4+0]*v.x; a3 += wh[2][4*k4+1]*v.y; a3 += wh[2][4*k4+2]*v.z; a3 += wh[2][4*k4+3]*v.w;
      }
      part[r][kq][j] = make_float4(a0, a1, a2, a3);
    }
    __syncthreads();                       // [B2] partials ready

    // gate combine: 512 tasks == 512 threads
    {
      const int rr = tid >> 7;
      const int jj = j;
      const float4 p0 = part[rr][0][jj];
      const float4 p1 = part[rr][1][jj];
      const float4 p2 = part[rr][2][jj];
      const float4 p3 = part[rr][3][jj];
      const float sr_ = p0.x + p1.x + p2.x + p3.x;
      const float sz_ = p0.y + p1.y + p2.y + p3.y;
      const float sxn = p0.z + p1.z + p2.z + p3.z;
      const float shn = p0.w + p1.w + p2.w + p3.w;
      const float rg = fast_sigmoid(sr_ + bir + bhr);
      const float zg = fast_sigmoid(sz_ + biz + bhz);
      const float ng = fast_tanh(sxn + bin_ + rg * (shn + bhn));
      const float hv = (1.f - zg) * ng + zg * h_s[rr][jj];
      h_s[rr][jj] = hv;
      if (STORE_ALL) {
        st_out(out + ((size_t)(r0 + rr) * T_SEQ + t) * H_DIM + jj, hv);
      } else if (t == T_SEQ - 1) {
        st_out(out + (size_t)(r0 + rr) * H_DIM + jj, hv);
      }
    }
    // next iteration's [B1] orders the h_s update vs. the partial phase.
  }
}

// FC head: out = fc2( BN( relu( fc1(h2_last) ) ) ); one row per block.
__global__ __launch_bounds__(64)
void head_kernel(const float* __restrict__ h2,     // (B, H)
                 const float* __restrict__ fc1_w,  // (64, 128)
                 const float* __restrict__ fc1_b,  // (64)
                 const float* __restrict__ fc2_w,  // (2, 64)
                 const float* __restrict__ fc2_b,  // (2)
                 const float* __restrict__ gamma,
                 const float* __restrict__ beta,
                 const float* __restrict__ mean,
                 const float* __restrict__ var,
                 float* __restrict__ out)          // (B, 2)
{
  const int row = blockIdx.x;
  const int j   = threadIdx.x;   // 0..63
  __shared__ __align__(16) float hrow[H_DIM];
  __shared__ __align__(16) float act[64];

  hrow[j]      = h2[(size_t)row * H_DIM + j];
  hrow[64 + j] = h2[(size_t)row * H_DIM + 64 + j];
  __syncthreads();

  float s = fc1_b[j];
  const float4* wr = reinterpret_cast<const float4*>(fc1_w + (size_t)j * H_DIM);
  #pragma unroll
  for (int k4 = 0; k4 < H_DIM / 4; ++k4) {
    const float4 w = wr[k4];
    const float4 h = reinterpret_cast<const float4*>(hrow)[k4];
    s += w.x * h.x + w.y * h.y + w.z * h.z + w.w * h.w;
  }
  s = fmaxf(s, 0.f);
  s = (s - mean[j]) * rsqrtf(var[j] + 1e-5f) * gamma[j] + beta[j];
  act[j] = s;
  __syncthreads();

  if (j < 2) {
    float o = fc2_b[j];
    #pragma unroll
    for (int k = 0; k < 64; ++k) o += fc2_w[(size_t)j * 64 + k] * act[k];
    out[(size_t)row * 2 + j] = o;
  }
}

} // namespace

extern "C" void kernel_launch(void* const* d_in, const int* in_sizes, int n_in,
                              void* d_out, int out_size, void* d_ws, size_t ws_size,
                              hipStream_t stream) {
  const float* x     = (const float*)d_in[0];
  const float* w_ih0 = (const float*)d_in[1];
  const float* w_hh0 = (const float*)d_in[2];
  const float* b_ih0 = (const float*)d_in[3];
  const float* b_hh0 = (const float*)d_in[4];
  const float* w_ih1 = (const float*)d_in[5];
  const float* w_hh1 = (const float*)d_in[6];
  const float* b_ih1 = (const float*)d_in[7];
  const float* b_hh1 = (const float*)d_in[8];
  const float* fc1_w = (const float*)d_in[9];
  const float* fc1_b = (const float*)d_in[10];
  const float* fc2_w = (const float*)d_in[11];
  const float* fc2_b = (const float*)d_in[12];
  const float* gamma = (const float*)d_in[13];
  const float* beta  = (const float*)d_in[14];
  const float* mean  = (const float*)d_in[15];
  const float* var   = (const float*)d_in[16];
  float* out = (float*)d_out;

  char* ws = (char*)d_ws;
  const size_t h2_bytes  = (size_t)B_SZ * H_DIM * sizeof(float);
  float* h2_last = (float*)ws;
  char*  h1_raw  = ws + h2_bytes;
  const size_t h1_elems = (size_t)B_SZ * T_SEQ * H_DIM;

  const dim3 gridG(B_SZ / RPB);
  const dim3 blockG(NTHR);

  if (ws_size >= h2_bytes + h1_elems * sizeof(float)) {
    float* h1 = (float*)h1_raw;
    gru_layer_kernel<64, float, float, true>
        <<<gridG, blockG, 0, stream>>>(x, w_ih0, w_hh0, b_ih0, b_hh0, h1);
    gru_layer_kernel<128, float, float, false>
        <<<gridG, blockG, 0, stream>>>(h1, w_ih1, w_hh1, b_ih1, b_hh1, h2_last);
  } else if (ws_size >= h2_bytes + h1_elems * sizeof(__hip_bfloat16)) {
    __hip_bfloat16* h1 = (__hip_bfloat16*)h1_raw;
    gru_layer_kernel<64, float, __hip_bfloat16, true>
        <<<gridG, blockG, 0, stream>>>(x, w_ih0, w_hh0, b_ih0, b_hh0, h1);
    gru_layer_kernel<128, __hip_bfloat16, float, false>
        <<<gridG, blockG, 0, stream>>>(h1, w_ih1, w_hh1, b_ih1, b_hh1, h2_last);
  } else {
    return;  // workspace too small for any valid plan — fail visibly
  }

  head_kernel<<<dim3(B_SZ), dim3(64), 0, stream>>>(
      h2_last, fc1_w, fc1_b, fc2_w, fc2_b, gamma, beta, mean, var, out);
}